// Round 2
// baseline (724.049 us; speedup 1.0000x reference)
//
#include <hip/hip_runtime.h>

typedef _Float16 f16;
typedef _Float16 f16x4 __attribute__((ext_vector_type(4)));
typedef _Float16 f16x8 __attribute__((ext_vector_type(8)));
typedef float    f32x4 __attribute__((ext_vector_type(4)));
typedef float    f32x16 __attribute__((ext_vector_type(16)));

#define MFMA32(a,b,c) __builtin_amdgcn_mfma_f32_32x32x16_f16((a),(b),(c),0,0,0)

// ---------------- FFT-layout matrices (exact 0/+-1 entries) ----------------
__device__ __forceinline__ float T_val(int rr, int cc) {
  int p = rr >> 2, f = rr & 3;
  int c = cc >> 2, d = (cc >> 1) & 1, e = cc & 1;
  int q = f & 1;
  int m = (p * c + 2 * q * d) & 3;
  float cs = (m == 0) ? 1.f : (m == 2) ? -1.f : 0.f;
  float sn = (m == 1) ? 1.f : (m == 3) ? -1.f : 0.f;
  if (f < 2) return (e == 0) ? cs : sn;
  return (e == 0) ? -sn : cs;
}
__device__ __forceinline__ float U_val(int rr, int cc) {
  int p = rr >> 2, f = rr & 3;
  int c = cc >> 2, d = (cc >> 1) & 1, e = cc & 1;
  int q = f & 1;
  int m = (p * c + 2 * q * d) & 3;
  float cs = (m == 0) ? 1.f : (m == 2) ? -1.f : 0.f;
  float sn = (m == 1) ? 1.f : (m == 3) ? -1.f : 0.f;
  float v;
  if (f < 2) v = (e == 0) ? cs : -sn;
  else       v = (e == 0) ? sn : cs;
  return v * 0.125f;
}

// ---------------- P1: Wq_eff / Wk_eff (fp32) ----------------
__global__ void prep_qk(const float* __restrict__ Wq, const float* __restrict__ Wk,
                        float* __restrict__ WqE, float* __restrict__ WkE) {
  int b = blockIdx.x;
  int isK = b >> 11;
  int h = (b >> 8) & 7;
  int dd = b & 255;
  const float* W = isK ? Wk : Wq;
  float* E = isK ? WkE : WqE;
  int k = threadIdx.x;
  size_t base = (size_t)h * 65536;
  float v;
  if (h < 3) {
    v = W[base + (size_t)dd * 256 + k];
  } else {
    int g = dd >> 4, i = dd & 15;
    float s = 0.f;
    for (int ip = 0; ip < 16; ++ip) {
      float t = T_val(ip, i);
      if (t != 0.f) s += t * W[base + (size_t)(g * 16 + ip) * 256 + k];
    }
    v = s;
  }
  E[base + (size_t)dd * 256 + k] = v;
}

// ---------------- P2: Mt[h][d'][d] = (Wq_eff . Wk_eff^T)[d][d'] / 16 (fp16)
__global__ void prep_m(const float* __restrict__ WqE, const float* __restrict__ WkE,
                       f16* __restrict__ Mt) {
  __shared__ float Aq[32][33];
  __shared__ float Bk[32][33];
  int h = blockIdx.x >> 6;
  int dpt = (blockIdx.x >> 3) & 7;
  int dt = blockIdx.x & 7;
  int tid = threadIdx.x;
  int drow = tid & 31;
  int dprow4 = (tid >> 5) * 4;
  float acc0 = 0.f, acc1 = 0.f, acc2 = 0.f, acc3 = 0.f;
  int r = tid >> 3;
  int c0 = (tid & 7) * 4;
  for (int kt = 0; kt < 8; ++kt) {
    for (int jj = 0; jj < 4; ++jj) {
      Aq[r][c0 + jj] = WqE[(size_t)h * 65536 + (size_t)(dt * 32 + r) * 256 + kt * 32 + c0 + jj];
      Bk[r][c0 + jj] = WkE[(size_t)h * 65536 + (size_t)(dpt * 32 + r) * 256 + kt * 32 + c0 + jj];
    }
    __syncthreads();
    #pragma unroll
    for (int k = 0; k < 32; ++k) {
      float a = Aq[drow][k];
      acc0 += a * Bk[dprow4 + 0][k];
      acc1 += a * Bk[dprow4 + 1][k];
      acc2 += a * Bk[dprow4 + 2][k];
      acc3 += a * Bk[dprow4 + 3][k];
    }
    __syncthreads();
  }
  int d_ = dt * 32 + drow;
  size_t ob = (size_t)h * 65536 + (size_t)(dpt * 32 + dprow4) * 256 + d_;
  Mt[ob + 0 * 256] = (f16)(acc0 * 0.0625f);
  Mt[ob + 1 * 256] = (f16)(acc1 * 0.0625f);
  Mt[ob + 2 * 256] = (f16)(acc2 * 0.0625f);
  Mt[ob + 3 * 256] = (f16)(acc3 * 0.0625f);
}

// ---------------- P3: Wvt[h][k'][d] = ((T~^T Wv U~^T)/8/NUM_HEADS)[d][k'] (fp16)
__global__ void prep_v(const float* __restrict__ Wv, f16* __restrict__ Wvt) {
  __shared__ float Ts[16][16];
  __shared__ float Us[16][16];
  int h = blockIdx.x >> 8;
  int kp = blockIdx.x & 255;
  int tid = threadIdx.x;
  Ts[tid >> 4][tid & 15] = T_val(tid >> 4, tid & 15);
  Us[tid >> 4][tid & 15] = U_val(tid >> 4, tid & 15);
  __syncthreads();
  int d = tid;
  int g = d >> 4, i = d & 15;
  int gp = kp >> 4, fp = kp & 15;
  float s = 0.f;
  if (h < 3) {
    s = Wv[(size_t)h * 65536 + (size_t)d * 256 + kp];
  } else {
    for (int ip = 0; ip < 16; ++ip) {
      float tv = Ts[ip][i];
      if (tv != 0.f) {
        float inner = 0.f;
        for (int jj = 0; jj < 16; ++jj) {
          float uv = Us[fp][jj];
          if (uv != 0.f)
            inner += uv * Wv[(size_t)h * 65536 + (size_t)(g * 16 + ip) * 256 + gp * 16 + jj];
        }
        s += tv * inner;
      }
    }
  }
  Wvt[(size_t)h * 65536 + (size_t)kp * 256 + d] = (f16)(s * 0.125f);
}

// ---------------- helpers ----------------
__device__ __forceinline__ f16x8 cvt_lo(const f32x16& c) {
  f16x8 r;
  #pragma unroll
  for (int i = 0; i < 8; ++i) r[i] = (f16)c[i];
  return r;
}
__device__ __forceinline__ f16x8 cvt_hi(const f32x16& c) {
  f16x8 r;
  #pragma unroll
  for (int i = 0; i < 8; ++i) r[i] = (f16)c[8 + i];
  return r;
}
__device__ __forceinline__ f16x8 comb(f16x4 a, f16x4 b) {
  f16x8 r;
  #pragma unroll
  for (int i = 0; i < 4; ++i) { r[i] = a[i]; r[4 + i] = b[i]; }
  return r;
}

// softmax over t (rows) for this lane's column s; write P (with parity mask)
__device__ __forceinline__ void softmax_store(const f32x16& S, f16* Pb, int s, int H) {
  int s1 = s & 1;
  float mx = -1e30f;
  #pragma unroll
  for (int rr = 0; rr < 16; ++rr) {
    float v = ((rr & 1) == s1) ? S[rr] : -1e30f;
    mx = fmaxf(mx, v);
  }
  mx = fmaxf(mx, __shfl_xor(mx, 32));
  float e[16];
  float sum = 0.f;
  #pragma unroll
  for (int rr = 0; rr < 16; ++rr) {
    float v = ((rr & 1) == s1) ? __expf(S[rr] - mx) : 0.f;
    e[rr] = v;
    sum += v;
  }
  sum += __shfl_xor(sum, 32);
  float inv = 1.f / sum;
  int px = (s & 7) << 2;
  #pragma unroll
  for (int rr = 0; rr < 16; ++rr) {
    int t = (rr & 3) + 8 * (rr >> 2) + 4 * H;
    Pb[s * 32 + (t ^ px)] = (f16)(e[rr] * inv);
  }
}

// ---------------- Main fused kernel ----------------
// grid 512 (8 batches/block), 512 threads (8 waves), LDS = 163840 B:
//   Xs [256 rows][256] f16, row = b_local*32 + s, 16B-granule XOR swizzle (131072 B)
//   Pl [2 heads][8 b][32 s][32 t] f16, 4-granule XOR swizzle on t        (32768 B)
// Wave (bp = w>>1, j = w&1):
//   phase1: head 2r+j, batches {2bp, 2bp+1}: Y'=Mt.X^T -> chain scores -> softmax -> P
//   phase2: both heads, batches {2bp,2bp+1}, k'-half j: V=X.Wv -> chain PV into acc
__global__ __launch_bounds__(512, 2) void mha_main(
    const float* __restrict__ xg_all,
    const f16* __restrict__ MtG,
    const f16* __restrict__ WvtG,
    float* __restrict__ outG)
{
  extern __shared__ char smem[];
  f16* Xs = (f16*)smem;
  f16* Pl = (f16*)(smem + 131072);

  const int tid = threadIdx.x;
  const int w   = tid >> 6;
  const int l31 = tid & 31;
  const int H   = (tid >> 5) & 1;
  const int bp  = w >> 1;
  const int j   = w & 1;

  // ---- stage x: fp32 -> fp16, swizzled ----
  const float* xg = xg_all + (size_t)blockIdx.x * 65536;
  #pragma unroll 4
  for (int i = 0; i < 32; ++i) {
    int f4 = i * 512 + tid;
    int row = f4 >> 6;
    int col4 = (f4 & 63) << 2;
    f32x4 v = *(const f32x4*)(xg + (size_t)f4 * 4);
    f16x4 hv;
    hv[0] = (f16)v[0]; hv[1] = (f16)v[1]; hv[2] = (f16)v[2]; hv[3] = (f16)v[3];
    *(f16x4*)(Xs + row * 256 + (col4 ^ ((row & 7) << 3))) = hv;
  }
  __syncthreads();

  const int b0 = bp * 2, b1 = b0 + 1;
  const f16* Xr0 = Xs + (b0 * 32 + l31) * 256;
  const f16* Xr1 = Xs + (b1 * 32 + l31) * 256;
  const int rx = (l31 & 7) << 3;

  f32x16 acc[2][4];
  #pragma unroll
  for (int bb = 0; bb < 2; ++bb)
    #pragma unroll
    for (int t4 = 0; t4 < 4; ++t4)
      #pragma unroll
      for (int i = 0; i < 16; ++i) acc[bb][t4][i] = 0.f;

  for (int r = 0; r < 4; ++r) {
    // ================= phase 1 =================
    {
      const f16* MtH = MtG + (size_t)(2 * r + j) * 65536;
      f32x16 S0, S1;
      #pragma unroll
      for (int i = 0; i < 16; ++i) { S0[i] = 0.f; S1[i] = 0.f; }
      for (int dt = 0; dt < 8; ++dt) {
        f32x16 Y0, Y1;
        #pragma unroll
        for (int i = 0; i < 16; ++i) { Y0[i] = 0.f; Y1[i] = 0.f; }
        const f16* Arow = MtH + (size_t)(dt * 32 + l31) * 256 + H * 8;
        #pragma unroll 4
        for (int kt = 0; kt < 16; ++kt) {
          f16x8 a = *(const f16x8*)(Arow + kt * 16);
          int sc = (kt * 16 + H * 8) ^ rx;
          f16x8 xb0 = *(const f16x8*)(Xr0 + sc);
          f16x8 xb1 = *(const f16x8*)(Xr1 + sc);
          Y0 = MFMA32(a, xb0, Y0);
          Y1 = MFMA32(a, xb1, Y1);
        }
        // chain into scores: A = X sigma-fragments, B = cvt(Y)
        int c0 = (dt * 32 + 4 * H) ^ rx;
        int c1 = (dt * 32 + 4 * H + 8) ^ rx;
        int c2 = (dt * 32 + 16 + 4 * H) ^ rx;
        int c3 = (dt * 32 + 24 + 4 * H) ^ rx;
        f16x8 alo0 = comb(*(const f16x4*)(Xr0 + c0), *(const f16x4*)(Xr0 + c1));
        f16x8 ahi0 = comb(*(const f16x4*)(Xr0 + c2), *(const f16x4*)(Xr0 + c3));
        f16x8 alo1 = comb(*(const f16x4*)(Xr1 + c0), *(const f16x4*)(Xr1 + c1));
        f16x8 ahi1 = comb(*(const f16x4*)(Xr1 + c2), *(const f16x4*)(Xr1 + c3));
        S0 = MFMA32(alo0, cvt_lo(Y0), S0);
        S0 = MFMA32(ahi0, cvt_hi(Y0), S0);
        S1 = MFMA32(alo1, cvt_lo(Y1), S1);
        S1 = MFMA32(ahi1, cvt_hi(Y1), S1);
      }
      softmax_store(S0, Pl + (j * 8 + b0) * 1024, l31, H);
      softmax_store(S1, Pl + (j * 8 + b1) * 1024, l31, H);
    }
    __syncthreads();
    // ================= phase 2 =================
    #pragma unroll
    for (int hh = 0; hh < 2; ++hh) {
      const f16* WvH = WvtG + (size_t)(2 * r + hh) * 65536;
      const f16* Pb0 = Pl + (hh * 8 + b0) * 1024 + l31 * 32;
      const f16* Pb1 = Pl + (hh * 8 + b1) * 1024 + l31 * 32;
      int px = (l31 & 7) << 2;
      f16x8 P0lo = comb(*(const f16x4*)(Pb0 + ((4 * H) ^ px)),
                        *(const f16x4*)(Pb0 + ((4 * H + 8) ^ px)));
      f16x8 P0hi = comb(*(const f16x4*)(Pb0 + ((16 + 4 * H) ^ px)),
                        *(const f16x4*)(Pb0 + ((24 + 4 * H) ^ px)));
      f16x8 P1lo = comb(*(const f16x4*)(Pb1 + ((4 * H) ^ px)),
                        *(const f16x4*)(Pb1 + ((4 * H + 8) ^ px)));
      f16x8 P1hi = comb(*(const f16x4*)(Pb1 + ((16 + 4 * H) ^ px)),
                        *(const f16x4*)(Pb1 + ((24 + 4 * H) ^ px)));
      #pragma unroll
      for (int t4 = 0; t4 < 4; ++t4) {
        const f16* Wrow = WvH + (size_t)((j * 4 + t4) * 32 + l31) * 256 + H * 8;
        f32x16 V0, V1;
        #pragma unroll
        for (int i = 0; i < 16; ++i) { V0[i] = 0.f; V1[i] = 0.f; }
        #pragma unroll 4
        for (int kt = 0; kt < 16; ++kt) {
          f16x8 wv = *(const f16x8*)(Wrow + kt * 16);
          int sc = (kt * 16 + H * 8) ^ rx;
          f16x8 xa0 = *(const f16x8*)(Xr0 + sc);
          f16x8 xa1 = *(const f16x8*)(Xr1 + sc);
          V0 = MFMA32(xa0, wv, V0);
          V1 = MFMA32(xa1, wv, V1);
        }
        acc[0][t4] = MFMA32(cvt_lo(V0), P0lo, acc[0][t4]);
        acc[0][t4] = MFMA32(cvt_hi(V0), P0hi, acc[0][t4]);
        acc[1][t4] = MFMA32(cvt_lo(V1), P1lo, acc[1][t4]);
        acc[1][t4] = MFMA32(cvt_hi(V1), P1hi, acc[1][t4]);
      }
    }
    __syncthreads();
  }

  // ---- store out ----
  #pragma unroll
  for (int bb = 0; bb < 2; ++bb) {
    float* ob = outG + ((size_t)blockIdx.x * 8 + (bp * 2 + bb)) * 8192 + l31 * 256 + j * 128;
    #pragma unroll
    for (int t4 = 0; t4 < 4; ++t4) {
      #pragma unroll
      for (int q = 0; q < 4; ++q) {
        f32x4 v;
        v[0] = acc[bb][t4][q * 4 + 0];
        v[1] = acc[bb][t4][q * 4 + 1];
        v[2] = acc[bb][t4][q * 4 + 2];
        v[3] = acc[bb][t4][q * 4 + 3];
        *(f32x4*)(ob + t4 * 32 + q * 8 + H * 4) = v;
      }
    }
  }
}

// ---------------- launch ----------------
extern "C" void kernel_launch(void* const* d_in, const int* in_sizes, int n_in,
                              void* d_out, int out_size, void* d_ws, size_t ws_size,
                              hipStream_t stream) {
  const float* x  = (const float*)d_in[0];
  const float* Wq = (const float*)d_in[1];
  const float* Wk = (const float*)d_in[2];
  const float* Wv = (const float*)d_in[3];
  float* out = (float*)d_out;
  char* ws = (char*)d_ws;
  float* WqE = (float*)ws;                       // 2 MB
  float* WkE = (float*)(ws + 2097152);           // 2 MB
  f16*   Mt  = (f16*)(ws + 4194304);             // 1 MB fp16
  f16*   Wvt = (f16*)(ws + 5242880);             // 1 MB fp16

  prep_qk<<<4096, 256, 0, stream>>>(Wq, Wk, WqE, WkE);
  prep_m<<<512, 256, 0, stream>>>(WqE, WkE, Mt);
  prep_v<<<2048, 256, 0, stream>>>(Wv, Wvt);
  mha_main<<<512, 512, 163840, stream>>>(x, Mt, Wvt, out);
}